// Round 1
// 603.992 us; speedup vs baseline: 1.0642x; 1.0642x over previous
//
#include <hip/hip_runtime.h>

// CrossAttUnit: fused per-segment cross-attention.
//   yk = Y @ k ; yq = Yhat @ q  (H=256 -> D=64, split-bf16 MFMA, 3 products)
//   M  = (1/8) yk @ yq^T  (64x64, split-bf16 MFMA)
//   attn = softmax_rows(M) + 1e-6 ; W = attn / colsum(attn)
// One block (256 thr, 4 waves) per segment; B = 4096 blocks.
// V2: 32 KB LDS (5 blocks/CU), split-bf16 staging planes, in-register softmax.

#define H  256
#define D  64
#define L  64

typedef __attribute__((ext_vector_type(8))) short frag_b;   // 8 x bf16 (4 VGPR)
typedef __attribute__((ext_vector_type(4))) float frag_acc; // 4 x fp32

__device__ inline unsigned short f32_bf16_rne(float f) {
    unsigned u = __float_as_uint(f);
    u += 0x7FFFu + ((u >> 16) & 1u);   // round-to-nearest-even on sign-magnitude bits
    return (unsigned short)(u >> 16);
}
__device__ inline float bf16_f32(unsigned short h) {
    return __uint_as_float(((unsigned)h) << 16);
}

// Offset (in shorts) of element (row,col) in a 64x64 bf16 plane.
// Row = 128 B = 8 chunks of 16 B; chunk index XORed with row&7 so a
// 16-row column-strided ds_read_b128 lands on 8 distinct chunk positions
// (2-way bank aliasing = free). Same function on write and read sides.
__device__ inline int pswz(int row, int col) {
    return (row << 6) + ((((col >> 3) ^ row) & 7) << 3) + (col & 7);
}

// Transpose + hi/lo split k,q into ws:
//  planes[0]      = kT_hi[64][256], planes[16384]  = kT_lo
//  planes[32768]  = qT_hi,          planes[49152]  = qT_lo
__global__ void prep_kq(const float* __restrict__ k, const float* __restrict__ q,
                        unsigned short* __restrict__ planes) {
    int tid = blockIdx.x * 256 + threadIdx.x;            // 0..32767
    const float* src = (tid < H * D) ? k : q;
    int base = (tid < H * D) ? 0 : 2 * H * D;
    int e = tid & (H * D - 1);
    int h = e >> 6, d = e & 63;                          // k[h][d]
    float x = src[e];
    unsigned short hi = f32_bf16_rne(x);
    float rem = x - bf16_f32(hi);
    unsigned short lo = f32_bf16_rne(rem);
    int o = d * H + h;                                   // transposed [d][h]
    planes[base + o] = hi;
    planes[base + H * D + o] = lo;
}

__global__ __launch_bounds__(256, 5) void cross_attn(
        const float* __restrict__ yhat, const float* __restrict__ y,
        const unsigned short* __restrict__ planes, float* __restrict__ out) {
    // 4 swizzled bf16 planes: yk_hi | yk_lo | yq_hi | yq_lo = 32768 B exactly
    // -> 5 blocks/CU (160 KiB / 32 KiB). s_cs aliases the dead planes in phase 3.
    __shared__ __align__(16) unsigned short s_pl[4 * L * D];

    const int b    = blockIdx.x;
    const int tid  = threadIdx.x;
    const int wave = tid >> 6;
    const int lane = tid & 63;
    const int ln   = lane & 15;   // row-in-tile (A) / col-in-tile (B,C)
    const int kg   = lane >> 4;   // k-group quad

    // ================= Phase 1: projections =================
    // waves 0,1 -> yk rows 0-31 / 32-63 ; waves 2,3 -> yq rows 0-31 / 32-63
    const bool isQ = (wave >= 2);
    const float* src = isQ ? yhat : y;
    const frag_b* bph = (const frag_b*)(planes + (isQ ? 2 * H * D : 0)); // hi plane
    const frag_b* bpl = bph + (H * D) / 8;                               // lo plane
    const int rowbase = (wave & 1) * 32;

    const frag_acc zf = {0.f, 0.f, 0.f, 0.f};
    frag_acc acc[2][4];
    #pragma unroll
    for (int rt = 0; rt < 2; rt++)
        #pragma unroll
        for (int t = 0; t < 4; t++) acc[rt][t] = zf;

    const float* abase = src + ((size_t)b * L + rowbase + ln) * H + kg * 8;

    #pragma unroll 2
    for (int ks = 0; ks < 8; ks++) {
        const int kb = ks * 32;
        // issue all 4 global loads for this k-slice before converting
        float4 v[2][2];
        #pragma unroll
        for (int rt = 0; rt < 2; rt++) {
            const float4* ap = (const float4*)(abase + (size_t)rt * 16 * H + kb);
            v[rt][0] = ap[0];
            v[rt][1] = ap[1];
        }
        frag_b ah[2], al[2];
        #pragma unroll
        for (int rt = 0; rt < 2; rt++) {
            float xs[8] = {v[rt][0].x, v[rt][0].y, v[rt][0].z, v[rt][0].w,
                           v[rt][1].x, v[rt][1].y, v[rt][1].z, v[rt][1].w};
            #pragma unroll
            for (int j = 0; j < 8; j++) {
                unsigned short hb = f32_bf16_rne(xs[j]);
                ah[rt][j] = (short)hb;
                al[rt][j] = (short)f32_bf16_rne(xs[j] - bf16_f32(hb));
            }
        }
        #pragma unroll
        for (int t = 0; t < 4; t++) {
            int n = t * 16 + ln;
            frag_b bh = bph[n * (H / 8) + ks * 4 + kg];
            frag_b bl = bpl[n * (H / 8) + ks * 4 + kg];
            #pragma unroll
            for (int rt = 0; rt < 2; rt++) {
                acc[rt][t] = __builtin_amdgcn_mfma_f32_16x16x32_bf16(ah[rt], bh, acc[rt][t], 0, 0, 0);
                acc[rt][t] = __builtin_amdgcn_mfma_f32_16x16x32_bf16(ah[rt], bl, acc[rt][t], 0, 0, 0);
                acc[rt][t] = __builtin_amdgcn_mfma_f32_16x16x32_bf16(al[rt], bh, acc[rt][t], 0, 0, 0);
            }
        }
    }

    // Epilogue: split each f32 result once into (hi,lo) bf16 and store to the
    // swizzled planes. C/D layout: col = lane&15, row = (lane>>4)*4 + i (m89/m91).
    // Phase 2 then consumes bf16 directly -> no redundant re-conversion.
    {
        unsigned short* dstH = s_pl + (isQ ? 2 * L * D : 0);
        unsigned short* dstL = dstH + L * D;
        #pragma unroll
        for (int rt = 0; rt < 2; rt++)
            #pragma unroll
            for (int t = 0; t < 4; t++)
                #pragma unroll
                for (int i = 0; i < 4; i++) {
                    int row = rowbase + rt * 16 + kg * 4 + i;
                    int col = t * 16 + ln;
                    float x = acc[rt][t][i];
                    unsigned short hb = f32_bf16_rne(x);
                    int o = pswz(row, col);
                    dstH[o] = hb;
                    dstL[o] = f32_bf16_rne(x - bf16_f32(hb));
                }
    }
    __syncthreads();

    // ================= Phase 2: M = (1/8) * yk @ yq^T =================
    // wave w -> M rows w*16 .. w*16+15, all 64 cols. Pure ds_read_b128 + MFMA.
    const unsigned short* ykH = s_pl;
    const unsigned short* ykL = s_pl + L * D;
    const unsigned short* yqH = s_pl + 2 * L * D;
    const unsigned short* yqL = s_pl + 3 * L * D;

    frag_acc mac[4];
    #pragma unroll
    for (int t = 0; t < 4; t++) mac[t] = zf;

    #pragma unroll
    for (int dk = 0; dk < 2; dk++) {
        const int colb = dk * 32 + kg * 8;
        frag_b ah = *(const frag_b*)(ykH + pswz(wave * 16 + ln, colb));
        frag_b al = *(const frag_b*)(ykL + pswz(wave * 16 + ln, colb));
        #pragma unroll
        for (int t = 0; t < 4; t++) {
            frag_b bh = *(const frag_b*)(yqH + pswz(t * 16 + ln, colb));
            frag_b bl = *(const frag_b*)(yqL + pswz(t * 16 + ln, colb));
            mac[t] = __builtin_amdgcn_mfma_f32_16x16x32_bf16(ah, bh, mac[t], 0, 0, 0);
            mac[t] = __builtin_amdgcn_mfma_f32_16x16x32_bf16(ah, bl, mac[t], 0, 0, 0);
            mac[t] = __builtin_amdgcn_mfma_f32_16x16x32_bf16(al, bh, mac[t], 0, 0, 0);
        }
    }
    __syncthreads();   // all plane reads drained -> safe to alias s_cs onto s_pl

    // ================= Phase 3: softmax rows + column-normalize, in-register ======
    // Lane holds M[row = wave*16 + kg*4 + i][col = t*16 + ln] in mac[t][i].
    // Row reduce = max/sum over t (in-lane) + 4-level shfl_xor within the 16-lane
    // kg-group. Column reduce = sum over i (in-lane) + shfl_xor over kg (16,32),
    // then tiny cross-wave s_cs.
    float* s_cs = (float*)s_pl;   // 4 waves * 64 cols, aliases dead planes

    float a[4][4];
    float colpart[4] = {0.f, 0.f, 0.f, 0.f};
    #pragma unroll
    for (int i = 0; i < 4; i++) {
        float v0 = 0.125f * mac[0][i], v1 = 0.125f * mac[1][i];
        float v2 = 0.125f * mac[2][i], v3 = 0.125f * mac[3][i];
        float mx = fmaxf(fmaxf(v0, v1), fmaxf(v2, v3));
        #pragma unroll
        for (int off = 8; off >= 1; off >>= 1) mx = fmaxf(mx, __shfl_xor(mx, off, 64));
        float e0 = __expf(v0 - mx), e1 = __expf(v1 - mx);
        float e2 = __expf(v2 - mx), e3 = __expf(v3 - mx);
        float s = (e0 + e1) + (e2 + e3);
        #pragma unroll
        for (int off = 8; off >= 1; off >>= 1) s += __shfl_xor(s, off, 64);
        float rs = 1.f / s;
        a[0][i] = e0 * rs + 1e-6f; a[1][i] = e1 * rs + 1e-6f;
        a[2][i] = e2 * rs + 1e-6f; a[3][i] = e3 * rs + 1e-6f;
        colpart[0] += a[0][i]; colpart[1] += a[1][i];
        colpart[2] += a[2][i]; colpart[3] += a[3][i];
    }
    #pragma unroll
    for (int t = 0; t < 4; t++) {
        colpart[t] += __shfl_xor(colpart[t], 16, 64);   // sum across kg groups:
        colpart[t] += __shfl_xor(colpart[t], 32, 64);   // full per-wave column sum
    }
    // each lane writes one distinct column's partial (its kg picks which t)
    s_cs[wave * 64 + kg * 16 + ln] = colpart[kg];
    __syncthreads();

    float* ob = out + (size_t)b * (L * L);
    #pragma unroll
    for (int t = 0; t < 4; t++) {
        int c = t * 16 + ln;
        float inv = 1.f / (s_cs[c] + s_cs[64 + c] + s_cs[128 + c] + s_cs[192 + c]);
        #pragma unroll
        for (int i = 0; i < 4; i++)
            ob[(wave * 16 + kg * 4 + i) * 64 + c] = a[t][i] * inv;
    }
}

extern "C" void kernel_launch(void* const* d_in, const int* in_sizes, int n_in,
                              void* d_out, int out_size, void* d_ws, size_t ws_size,
                              hipStream_t stream) {
    const float* yhat = (const float*)d_in[0];
    const float* y    = (const float*)d_in[1];
    const float* k    = (const float*)d_in[2];
    const float* q    = (const float*)d_in[3];
    float* outp = (float*)d_out;
    unsigned short* planes = (unsigned short*)d_ws;   // 4 planes * 16384 ushort = 128 KB

    const int N = in_sizes[0] / H;    // 262144
    const int B = N / L;              // 4096

    prep_kq<<<(2 * H * D) / 256, 256, 0, stream>>>(k, q, planes);
    cross_attn<<<B, 256, 0, stream>>>(yhat, y, planes, outp);
}